// Round 8
// baseline (567.272 us; speedup 1.0000x reference)
//
#include <hip/hip_runtime.h>

#define BB 4096
#define TT 256
#define FF 32
#define HH 6

#define DPP_XOR1 0xB1   // quad_perm(1,0,3,2)
#define DPP_XOR2 0x4E   // quad_perm(2,3,0,1)
#define DPP_XOR3 0x1B   // quad_perm(3,2,1,0)
#define DPP_HALF 0x141  // row_half_mirror = xor 7 within 8-lane half-rows

__device__ __forceinline__ float fast_rcp(float x) { return __builtin_amdgcn_rcpf(x); }
__device__ __forceinline__ float sigmoidf(float x) { return fast_rcp(1.0f + __expf(-x)); }

template <int CTRL>
__device__ __forceinline__ float dppf(float x) {
    return __int_as_float(__builtin_amdgcn_update_dpp(
        0, __float_as_int(x), CTRL, 0xF, 0xF, true));
}
__device__ __forceinline__ float dpp_xor4(float x) {
    return dppf<DPP_HALF>(dppf<DPP_XOR3>(x));
}

// K1: 4 lanes per (b,t) item, output-split attention+projection.
// Lane q of a quad owns score outputs f2 in [q*8, q*8+8).
// acc[] is gate-major (Wl column order); epilogue transposes to [unit][i,f,g,o].
__global__ __launch_bounds__(256, 4) void k_attn_xz(
    const float* __restrict__ x, const float* __restrict__ Wa, const float* __restrict__ ba,
    const float* __restrict__ Wl, const float* __restrict__ bl, float* __restrict__ xz)
{
    const int tid = blockIdx.x * 256 + threadIdx.x;
    const int item = tid >> 2;        // (b,t) index
    const int q = tid & 3;            // quad sub-lane
    const float* xp = x + (size_t)item * FF;

    // full x row (quad lanes share addresses -> L1 broadcast)
    float xv[FF];
#pragma unroll
    for (int c = 0; c < FF / 4; ++c) {
        const float4 v = *(const float4*)(xp + c * 4);
        xv[c*4+0] = v.x; xv[c*4+1] = v.y; xv[c*4+2] = v.z; xv[c*4+3] = v.w;
    }

    // phase A: my 8 scores
    float s[8];
    {
        const float4 b0 = *(const float4*)(ba + q * 8);
        const float4 b1 = *(const float4*)(ba + q * 8 + 4);
        s[0]=b0.x; s[1]=b0.y; s[2]=b0.z; s[3]=b0.w;
        s[4]=b1.x; s[5]=b1.y; s[6]=b1.z; s[7]=b1.w;
    }
#pragma unroll
    for (int f = 0; f < FF; ++f) {
        const float4 w0 = *(const float4*)(Wa + f * FF + q * 8);
        const float4 w1 = *(const float4*)(Wa + f * FF + q * 8 + 4);
        const float xf = xv[f];
        s[0] = fmaf(xf, w0.x, s[0]); s[1] = fmaf(xf, w0.y, s[1]);
        s[2] = fmaf(xf, w0.z, s[2]); s[3] = fmaf(xf, w0.w, s[3]);
        s[4] = fmaf(xf, w1.x, s[4]); s[5] = fmaf(xf, w1.y, s[5]);
        s[6] = fmaf(xf, w1.z, s[6]); s[7] = fmaf(xf, w1.w, s[7]);
    }

    // softmax over all 32 (local 8 + quad combine)
    float mx = s[0];
#pragma unroll
    for (int k = 1; k < 8; ++k) mx = fmaxf(mx, s[k]);
    mx = fmaxf(mx, dppf<DPP_XOR1>(mx));
    mx = fmaxf(mx, dppf<DPP_XOR2>(mx));
    float e[8];
    float sum = 0.0f;
#pragma unroll
    for (int k = 0; k < 8; ++k) { e[k] = __expf(s[k] - mx); sum += e[k]; }
    sum += dppf<DPP_XOR1>(sum);
    sum += dppf<DPP_XOR2>(sum);
    const float r = fast_rcp(sum);

    // phase B: my 8 features' contribution (own x re-loaded from L1; static indexing)
    float own[8];
    {
        const float4 o0 = *(const float4*)(xp + q * 8);
        const float4 o1 = *(const float4*)(xp + q * 8 + 4);
        own[0]=o0.x; own[1]=o0.y; own[2]=o0.z; own[3]=o0.w;
        own[4]=o1.x; own[5]=o1.y; own[6]=o1.z; own[7]=o1.w;
    }
    float acc[24];
#pragma unroll
    for (int g = 0; g < 24; ++g) acc[g] = 0.0f;
#pragma unroll
    for (int k = 0; k < 8; ++k) {
        const float p = own[k] * e[k];           // feat * e (r applied at end)
        const float* wl = Wl + (size_t)(q * 8 + k) * 24;
#pragma unroll
        for (int c = 0; c < 6; ++c) {
            const float4 w = *(const float4*)(wl + c * 4);
            acc[c*4+0] = fmaf(p, w.x, acc[c*4+0]);
            acc[c*4+1] = fmaf(p, w.y, acc[c*4+1]);
            acc[c*4+2] = fmaf(p, w.z, acc[c*4+2]);
            acc[c*4+3] = fmaf(p, w.w, acc[c*4+3]);
        }
    }
    // quad combine -> every lane holds the full 24 gate-major sums
#pragma unroll
    for (int g = 0; g < 24; ++g) acc[g] += dppf<DPP_XOR1>(acc[g]);
#pragma unroll
    for (int g = 0; g < 24; ++g) acc[g] += dppf<DPP_XOR2>(acc[g]);

    // epilogue: transpose gate-major -> [unit][i,f,g,o].
    // Chunk for unit jp = (acc[jp], acc[6+jp], acc[12+jp], acc[18+jp]) * r + bl[gate*6+jp].
    float* op = xz + (size_t)item * 24;
    // lane q writes unit jp = q (static cndmask selection, no runtime array index)
    {
        const float ai = (q == 0) ? acc[0]  : (q == 1) ? acc[1]  : (q == 2) ? acc[2]  : acc[3];
        const float af = (q == 0) ? acc[6]  : (q == 1) ? acc[7]  : (q == 2) ? acc[8]  : acc[9];
        const float ag = (q == 0) ? acc[12] : (q == 1) ? acc[13] : (q == 2) ? acc[14] : acc[15];
        const float ao = (q == 0) ? acc[18] : (q == 1) ? acc[19] : (q == 2) ? acc[20] : acc[21];
        float4 o;
        o.x = fmaf(ai, r, bl[0  + q]);
        o.y = fmaf(af, r, bl[6  + q]);
        o.z = fmaf(ag, r, bl[12 + q]);
        o.w = fmaf(ao, r, bl[18 + q]);
        *(float4*)(op + q * 4) = o;
    }
    // lanes 0,1 also write units 4,5
    if (q < 2) {
        const int jp = 4 + q;
        const float ai = (q == 0) ? acc[4]  : acc[5];
        const float af = (q == 0) ? acc[10] : acc[11];
        const float ag = (q == 0) ? acc[16] : acc[17];
        const float ao = (q == 0) ? acc[22] : acc[23];
        float4 o;
        o.x = fmaf(ai, r, bl[0  + jp]);
        o.y = fmaf(af, r, bl[6  + jp]);
        o.z = fmaf(ag, r, bl[12 + jp]);
        o.w = fmaf(ao, r, bl[18 + jp]);
        *(float4*)(op + jp * 4) = o;
    }
}

// K2: LSTM scan. 8 lanes/batch, DPP cross-lane, W10 in LDS, deep prefetch.
__global__ __launch_bounds__(64, 1) void k_scan(
    const float* __restrict__ xz, const float* __restrict__ Ul,
    const float* __restrict__ W10, const float* __restrict__ b10,
    const float* __restrict__ Wo, const float* __restrict__ bo,
    float* __restrict__ out)
{
    const int lane = threadIdx.x;
    const int j = lane & 7;
    const int b = blockIdx.x * 8 + (lane >> 3);
    const bool real = (j < HH);
    const int jc = real ? j : 0;

    __shared__ __align__(16) float w10s[TT * HH * 10 + 64];  // +junk row for t=256 prefetch
    {
        const float2* src = (const float2*)W10;
        float2* dst = (float2*)w10s;
        for (int i = lane; i < (TT * HH * 10) / 2; i += 64) dst[i] = src[i];
    }
    __syncthreads();

    float Ui[8], Uf[8], Ug[8], Uo[8];
#pragma unroll
    for (int m = 0; m < 8; ++m) {
        const int src = j ^ m;
        const bool ok = real && (src < HH);
        const float* row = Ul + (ok ? src : 0) * 24;
        Ui[m] = ok ? row[0  + j] : 0.0f;
        Uf[m] = ok ? row[6  + j] : 0.0f;
        Ug[m] = ok ? row[12 + j] : 0.0f;
        Uo[m] = ok ? row[18 + j] : 0.0f;
    }

    float hl[8];           // ovec = ov*ec of unit (j^m); true h = ovec * r2
    float r2 = 1.0f;
    float c = 0.0f;
    float y[10];
#pragma unroll
    for (int m = 0; m < 8; ++m) hl[m] = 0.0f;
#pragma unroll
    for (int p = 0; p < 10; ++p) y[p] = 0.0f;

    float2 wrow[5];
#pragma unroll
    for (int q = 0; q < 5; ++q) wrow[q] = *(const float2*)(w10s + jc * 10 + q * 2);

    const float* xb = xz + (size_t)b * (TT * 24) + j * 4;

    auto step = [&](const float4 z4, const int t) {
        float di0 = hl[0]*Ui[0], di1 = hl[4]*Ui[4];
        float df0 = hl[0]*Uf[0], df1 = hl[4]*Uf[4];
        float dg0 = hl[0]*Ug[0], dg1 = hl[4]*Ug[4];
        float dq0 = hl[0]*Uo[0], dq1 = hl[4]*Uo[4];
#pragma unroll
        for (int m = 1; m < 4; ++m) {
            di0 = fmaf(hl[m], Ui[m], di0); di1 = fmaf(hl[m+4], Ui[m+4], di1);
            df0 = fmaf(hl[m], Uf[m], df0); df1 = fmaf(hl[m+4], Uf[m+4], df1);
            dg0 = fmaf(hl[m], Ug[m], dg0); dg1 = fmaf(hl[m+4], Ug[m+4], dg1);
            dq0 = fmaf(hl[m], Uo[m], dq0); dq1 = fmaf(hl[m+4], Uo[m+4], dq1);
        }
        const float zi = fmaf(di0 + di1, r2, z4.x);
        const float zf = fmaf(df0 + df1, r2, z4.y);
        const float zg = fmaf(dg0 + dg1, r2, z4.z);
        const float zo = fmaf(dq0 + dq1, r2, z4.w);

        const float iv = sigmoidf(zi);
        const float fv = sigmoidf(zf);
        const float ov = sigmoidf(zo);

        const float eg = real ? __expf(zg) : 0.0f;
        float s1 = eg;
        s1 += dppf<DPP_XOR1>(s1);
        s1 += dppf<DPP_XOR2>(s1);
        s1 += dpp_xor4(s1);
        c = fmaf(fv, c, (iv * eg) * fast_rcp(s1));

        const float cmsk = real ? c : -1e30f;
        float m2 = fmaxf(cmsk, dppf<DPP_XOR1>(cmsk));
        m2 = fmaxf(m2, dppf<DPP_XOR2>(m2));
        m2 = fmaxf(m2, dpp_xor4(m2));
        const float ec = real ? __expf(c - m2) : 0.0f;
        float s2 = ec;
        s2 += dppf<DPP_XOR1>(s2);
        s2 += dppf<DPP_XOR2>(s2);
        s2 += dpp_xor4(s2);

        const float ovec = ov * ec;
        hl[0] = ovec;
        hl[1] = dppf<DPP_XOR1>(ovec);
        hl[2] = dppf<DPP_XOR2>(ovec);
        hl[3] = dppf<DPP_XOR3>(ovec);
        const float h7 = dppf<DPP_HALF>(ovec);
        hl[7] = h7;
        hl[6] = dppf<DPP_XOR1>(h7);
        hl[5] = dppf<DPP_XOR2>(h7);
        hl[4] = dppf<DPP_XOR3>(h7);
        r2 = fast_rcp(s2);
        const float hn = ovec * r2;

        float2 wn[5];
        const int rn = ((t + 1) * HH + jc) * 10;
#pragma unroll
        for (int q = 0; q < 5; ++q) wn[q] = *(const float2*)(w10s + rn + q * 2);
#pragma unroll
        for (int q = 0; q < 5; ++q) {
            y[2*q]   = fmaf(hn, wrow[q].x, y[2*q]);
            y[2*q+1] = fmaf(hn, wrow[q].y, y[2*q+1]);
        }
#pragma unroll
        for (int q = 0; q < 5; ++q) wrow[q] = wn[q];
    };

    float4 A[4], B[4], C[4], D[4];
    const float* xp = xb;

#define LDBLK(Bf, dt0)                                                  \
    { _Pragma("unroll") for (int q = 0; q < 4; ++q)                     \
        Bf[q] = *(const float4*)(xp + (dt0 + q) * 24); }

    LDBLK(A, 0); LDBLK(B, 4); LDBLK(C, 8);

#pragma unroll 1
    for (int it = 0; it < 16; ++it) {
        const int t0 = it * 16;
        LDBLK(D, 12);
        step(A[0], t0 + 0);  step(A[1], t0 + 1);  step(A[2], t0 + 2);  step(A[3], t0 + 3);
        LDBLK(A, 16);
        step(B[0], t0 + 4);  step(B[1], t0 + 5);  step(B[2], t0 + 6);  step(B[3], t0 + 7);
        LDBLK(B, 20);
        step(C[0], t0 + 8);  step(C[1], t0 + 9);  step(C[2], t0 + 10); step(C[3], t0 + 11);
        LDBLK(C, 24);
        step(D[0], t0 + 12); step(D[1], t0 + 13); step(D[2], t0 + 14); step(D[3], t0 + 15);
        xp += 16 * 24;
    }
#undef LDBLK

#pragma unroll
    for (int p = 0; p < 10; ++p) {
        float v = y[p];
        v += dppf<DPP_XOR1>(v);
        v += dppf<DPP_XOR2>(v);
        v += dpp_xor4(v);
        y[p] = v;
    }

    float o8 = bo[j];
#pragma unroll
    for (int p = 0; p < 10; ++p) o8 = fmaf(y[p] + b10[p], Wo[p * 8 + j], o8);
    out[(size_t)b * 8 + j] = o8;
}

extern "C" void kernel_launch(void* const* d_in, const int* in_sizes, int n_in,
                              void* d_out, int out_size, void* d_ws, size_t ws_size,
                              hipStream_t stream) {
    const float* x   = (const float*)d_in[0];
    const float* Wa  = (const float*)d_in[1];
    const float* ba  = (const float*)d_in[2];
    const float* Wl  = (const float*)d_in[3];
    const float* Ul  = (const float*)d_in[4];
    const float* bl  = (const float*)d_in[5];
    const float* W10 = (const float*)d_in[6];
    const float* b10 = (const float*)d_in[7];
    const float* Wo  = (const float*)d_in[8];
    const float* bo  = (const float*)d_in[9];
    float* out = (float*)d_out;
    float* xz  = (float*)d_ws;   // BB*TT*24*4 = 96 MiB (+ slack for tail prefetch)

    hipLaunchKernelGGL(k_attn_xz, dim3(BB * TT * 4 / 256), dim3(256), 0, stream,
                       x, Wa, ba, Wl, bl, xz);
    hipLaunchKernelGGL(k_scan, dim3(BB / 8), dim3(64), 0, stream,
                       xz, Ul, W10, b10, Wo, bo, out);
}

// Round 9
// 427.195 us; speedup vs baseline: 1.3279x; 1.3279x over previous
//
#include <hip/hip_runtime.h>

#define BB 4096
#define TT 256
#define FF 32
#define HH 6

#define DPP_XOR1 0xB1   // quad_perm(1,0,3,2)
#define DPP_XOR2 0x4E   // quad_perm(2,3,0,1)
#define DPP_XOR3 0x1B   // quad_perm(3,2,1,0)
#define DPP_HALF 0x141  // row_half_mirror = xor 7 within 8-lane half-rows

__device__ __forceinline__ float fast_rcp(float x) { return __builtin_amdgcn_rcpf(x); }
__device__ __forceinline__ float sigmoidf(float x) { return fast_rcp(1.0f + __expf(-x)); }

template <int CTRL>
__device__ __forceinline__ float dppf(float x) {
    return __int_as_float(__builtin_amdgcn_update_dpp(
        0, __float_as_int(x), CTRL, 0xF, 0xF, true));
}
__device__ __forceinline__ float dpp_xor4(float x) {
    return dppf<DPP_HALF>(dppf<DPP_XOR3>(x));
}

// K1: 1 thread per (b,t) item; x row in LDS (stride 33 -> conflict-free);
// output-tiled online attention: per 8-score tile {matvec -> exp -> project},
// weights stay wave-uniform (SGPR scalar loads). Live set ~40 regs.
// Output layout: [b][t][j=0..5][gate i,f,g,o] fp32 (24 floats / item).
__global__ __launch_bounds__(256, 4) void k_attn_xz(
    const float* __restrict__ x, const float* __restrict__ Wa, const float* __restrict__ ba,
    const float* __restrict__ Wl, const float* __restrict__ bl, float* __restrict__ xz)
{
    const int tid = blockIdx.x * 256 + threadIdx.x;
    const int lt = threadIdx.x;
    __shared__ float xs[256 * 33];

    const float* xp = x + (size_t)tid * FF;
    float* myx = xs + lt * 33;

    // stage own x row into LDS (coalesced global read, b32 LDS writes)
#pragma unroll
    for (int c = 0; c < FF / 4; ++c) {
        const float4 v = *(const float4*)(xp + c * 4);
        myx[c*4+0] = v.x; myx[c*4+1] = v.y; myx[c*4+2] = v.z; myx[c*4+3] = v.w;
    }
    // own-row access only -> no barrier; compiler inserts lgkmcnt waits.

    float acc[24];
#pragma unroll
    for (int g = 0; g < 24; ++g) acc[g] = 0.0f;
    float sum = 0.0f;

#pragma unroll
    for (int t = 0; t < 4; ++t) {            // score tile [t*8, t*8+8)
        // s_tile = ba + x @ Wa[:, tile]
        float s[8];
#pragma unroll
        for (int k = 0; k < 8; ++k) s[k] = ba[t * 8 + k];
#pragma unroll
        for (int f = 0; f < FF; ++f) {
            const float xf = myx[f];
            const float* wr = Wa + f * FF + t * 8;   // wave-uniform -> SGPR
#pragma unroll
            for (int k = 0; k < 8; ++k) s[k] = fmaf(xf, wr[k], s[k]);
        }
        // exp (no max-sub: |s| small, fp32 safe) + project into acc
#pragma unroll
        for (int k = 0; k < 8; ++k) {
            const float e = __expf(s[k]);
            sum += e;
            const float p = myx[t * 8 + k] * e;      // feat*e (1/sum applied at end)
            const float* wl = Wl + (size_t)(t * 8 + k) * 24;  // wave-uniform -> SGPR
#pragma unroll
            for (int g = 0; g < 24; ++g) acc[g] = fmaf(p, wl[g], acc[g]);
        }
    }
    const float r = fast_rcp(sum);

    // epilogue: gate-major acc -> [unit][i,f,g,o], scale by r, add bl
    float* op = xz + (size_t)tid * 24;
#pragma unroll
    for (int jp = 0; jp < HH; ++jp) {
        float4 v;
        v.x = fmaf(acc[0  + jp], r, bl[0  + jp]);   // i
        v.y = fmaf(acc[6  + jp], r, bl[6  + jp]);   // f
        v.z = fmaf(acc[12 + jp], r, bl[12 + jp]);   // g pre-act
        v.w = fmaf(acc[18 + jp], r, bl[18 + jp]);   // o
        *(float4*)(op + jp * 4) = v;
    }
}

// K2 (unchanged, passing): LSTM scan. 8 lanes/batch, DPP cross-lane,
// W10 in LDS, 12-step-deep prefetch.
__global__ __launch_bounds__(64, 1) void k_scan(
    const float* __restrict__ xz, const float* __restrict__ Ul,
    const float* __restrict__ W10, const float* __restrict__ b10,
    const float* __restrict__ Wo, const float* __restrict__ bo,
    float* __restrict__ out)
{
    const int lane = threadIdx.x;
    const int j = lane & 7;
    const int b = blockIdx.x * 8 + (lane >> 3);
    const bool real = (j < HH);
    const int jc = real ? j : 0;

    __shared__ __align__(16) float w10s[TT * HH * 10 + 64];  // +junk row for t=256 prefetch
    {
        const float2* src = (const float2*)W10;
        float2* dst = (float2*)w10s;
        for (int i = lane; i < (TT * HH * 10) / 2; i += 64) dst[i] = src[i];
    }
    __syncthreads();

    float Ui[8], Uf[8], Ug[8], Uo[8];
#pragma unroll
    for (int m = 0; m < 8; ++m) {
        const int src = j ^ m;
        const bool ok = real && (src < HH);
        const float* row = Ul + (ok ? src : 0) * 24;
        Ui[m] = ok ? row[0  + j] : 0.0f;
        Uf[m] = ok ? row[6  + j] : 0.0f;
        Ug[m] = ok ? row[12 + j] : 0.0f;
        Uo[m] = ok ? row[18 + j] : 0.0f;
    }

    float hl[8];           // ovec = ov*ec of unit (j^m); true h = ovec * r2
    float r2 = 1.0f;
    float c = 0.0f;
    float y[10];
#pragma unroll
    for (int m = 0; m < 8; ++m) hl[m] = 0.0f;
#pragma unroll
    for (int p = 0; p < 10; ++p) y[p] = 0.0f;

    float2 wrow[5];
#pragma unroll
    for (int q = 0; q < 5; ++q) wrow[q] = *(const float2*)(w10s + jc * 10 + q * 2);

    const float* xb = xz + (size_t)b * (TT * 24) + j * 4;

    auto step = [&](const float4 z4, const int t) {
        float di0 = hl[0]*Ui[0], di1 = hl[4]*Ui[4];
        float df0 = hl[0]*Uf[0], df1 = hl[4]*Uf[4];
        float dg0 = hl[0]*Ug[0], dg1 = hl[4]*Ug[4];
        float dq0 = hl[0]*Uo[0], dq1 = hl[4]*Uo[4];
#pragma unroll
        for (int m = 1; m < 4; ++m) {
            di0 = fmaf(hl[m], Ui[m], di0); di1 = fmaf(hl[m+4], Ui[m+4], di1);
            df0 = fmaf(hl[m], Uf[m], df0); df1 = fmaf(hl[m+4], Uf[m+4], df1);
            dg0 = fmaf(hl[m], Ug[m], dg0); dg1 = fmaf(hl[m+4], Ug[m+4], dg1);
            dq0 = fmaf(hl[m], Uo[m], dq0); dq1 = fmaf(hl[m+4], Uo[m+4], dq1);
        }
        const float zi = fmaf(di0 + di1, r2, z4.x);
        const float zf = fmaf(df0 + df1, r2, z4.y);
        const float zg = fmaf(dg0 + dg1, r2, z4.z);
        const float zo = fmaf(dq0 + dq1, r2, z4.w);

        const float iv = sigmoidf(zi);
        const float fv = sigmoidf(zf);
        const float ov = sigmoidf(zo);

        const float eg = real ? __expf(zg) : 0.0f;
        float s1 = eg;
        s1 += dppf<DPP_XOR1>(s1);
        s1 += dppf<DPP_XOR2>(s1);
        s1 += dpp_xor4(s1);
        c = fmaf(fv, c, (iv * eg) * fast_rcp(s1));

        const float cmsk = real ? c : -1e30f;
        float m2 = fmaxf(cmsk, dppf<DPP_XOR1>(cmsk));
        m2 = fmaxf(m2, dppf<DPP_XOR2>(m2));
        m2 = fmaxf(m2, dpp_xor4(m2));
        const float ec = real ? __expf(c - m2) : 0.0f;
        float s2 = ec;
        s2 += dppf<DPP_XOR1>(s2);
        s2 += dppf<DPP_XOR2>(s2);
        s2 += dpp_xor4(s2);

        const float ovec = ov * ec;
        hl[0] = ovec;
        hl[1] = dppf<DPP_XOR1>(ovec);
        hl[2] = dppf<DPP_XOR2>(ovec);
        hl[3] = dppf<DPP_XOR3>(ovec);
        const float h7 = dppf<DPP_HALF>(ovec);
        hl[7] = h7;
        hl[6] = dppf<DPP_XOR1>(h7);
        hl[5] = dppf<DPP_XOR2>(h7);
        hl[4] = dppf<DPP_XOR3>(h7);
        r2 = fast_rcp(s2);
        const float hn = ovec * r2;

        float2 wn[5];
        const int rn = ((t + 1) * HH + jc) * 10;
#pragma unroll
        for (int q = 0; q < 5; ++q) wn[q] = *(const float2*)(w10s + rn + q * 2);
#pragma unroll
        for (int q = 0; q < 5; ++q) {
            y[2*q]   = fmaf(hn, wrow[q].x, y[2*q]);
            y[2*q+1] = fmaf(hn, wrow[q].y, y[2*q+1]);
        }
#pragma unroll
        for (int q = 0; q < 5; ++q) wrow[q] = wn[q];
    };

    float4 A[4], B[4], C[4], D[4];
    const float* xp = xb;

#define LDBLK(Bf, dt0)                                                  \
    { _Pragma("unroll") for (int q = 0; q < 4; ++q)                     \
        Bf[q] = *(const float4*)(xp + (dt0 + q) * 24); }

    LDBLK(A, 0); LDBLK(B, 4); LDBLK(C, 8);

#pragma unroll 1
    for (int it = 0; it < 16; ++it) {
        const int t0 = it * 16;
        LDBLK(D, 12);
        step(A[0], t0 + 0);  step(A[1], t0 + 1);  step(A[2], t0 + 2);  step(A[3], t0 + 3);
        LDBLK(A, 16);
        step(B[0], t0 + 4);  step(B[1], t0 + 5);  step(B[2], t0 + 6);  step(B[3], t0 + 7);
        LDBLK(B, 20);
        step(C[0], t0 + 8);  step(C[1], t0 + 9);  step(C[2], t0 + 10); step(C[3], t0 + 11);
        LDBLK(C, 24);
        step(D[0], t0 + 12); step(D[1], t0 + 13); step(D[2], t0 + 14); step(D[3], t0 + 15);
        xp += 16 * 24;
    }
#undef LDBLK

#pragma unroll
    for (int p = 0; p < 10; ++p) {
        float v = y[p];
        v += dppf<DPP_XOR1>(v);
        v += dppf<DPP_XOR2>(v);
        v += dpp_xor4(v);
        y[p] = v;
    }

    float o8 = bo[j];
#pragma unroll
    for (int p = 0; p < 10; ++p) o8 = fmaf(y[p] + b10[p], Wo[p * 8 + j], o8);
    out[(size_t)b * 8 + j] = o8;
}

extern "C" void kernel_launch(void* const* d_in, const int* in_sizes, int n_in,
                              void* d_out, int out_size, void* d_ws, size_t ws_size,
                              hipStream_t stream) {
    const float* x   = (const float*)d_in[0];
    const float* Wa  = (const float*)d_in[1];
    const float* ba  = (const float*)d_in[2];
    const float* Wl  = (const float*)d_in[3];
    const float* Ul  = (const float*)d_in[4];
    const float* bl  = (const float*)d_in[5];
    const float* W10 = (const float*)d_in[6];
    const float* b10 = (const float*)d_in[7];
    const float* Wo  = (const float*)d_in[8];
    const float* bo  = (const float*)d_in[9];
    float* out = (float*)d_out;
    float* xz  = (float*)d_ws;   // BB*TT*24*4 = 96 MiB (+ slack for tail prefetch)

    hipLaunchKernelGGL(k_attn_xz, dim3(BB * TT / 256), dim3(256), 0, stream,
                       x, Wa, ba, Wl, bl, xz);
    hipLaunchKernelGGL(k_scan, dim3(BB / 8), dim3(64), 0, stream,
                       xz, Ul, W10, b10, Wo, bo, out);
}

// Round 10
// 275.250 us; speedup vs baseline: 2.0609x; 1.5520x over previous
//
#include <hip/hip_runtime.h>

#define BB 4096
#define TT 256
#define FF 32
#define HH 6

#define DPP_XOR1 0xB1   // quad_perm(1,0,3,2)
#define DPP_XOR2 0x4E   // quad_perm(2,3,0,1)
#define DPP_XOR3 0x1B   // quad_perm(3,2,1,0)
#define DPP_HALF 0x141  // row_half_mirror = xor 7 within 8-lane half-rows

__device__ __forceinline__ float fast_rcp(float x) { return __builtin_amdgcn_rcpf(x); }
__device__ __forceinline__ float sigmoidf(float x) { return fast_rcp(1.0f + __expf(-x)); }

template <int CTRL>
__device__ __forceinline__ float dppf(float x) {
    return __int_as_float(__builtin_amdgcn_update_dpp(
        0, __float_as_int(x), CTRL, 0xF, 0xF, true));
}
__device__ __forceinline__ float dpp_xor4(float x) {
    return dppf<DPP_HALF>(dppf<DPP_XOR3>(x));
}

// K1: 1 thread per (b,t); x row in REGISTERS; weights via wave-uniform scalar
// loads; output-tiled (8 scores per tile) so peak live set ~66 floats.
// launch_bounds(256,2): VGPR cap 256 -> no rematerialization pressure.
// Output layout: [b][t][j=0..5][gate i,f,g,o] fp32 (24 floats / item).
__global__ __launch_bounds__(256, 2) void k_attn_xz(
    const float* __restrict__ x, const float* __restrict__ Wa, const float* __restrict__ ba,
    const float* __restrict__ Wl, const float* __restrict__ bl, float* __restrict__ xz)
{
    const int tid = blockIdx.x * 256 + threadIdx.x;
    const float* xp = x + (size_t)tid * FF;

    float xv[FF];
#pragma unroll
    for (int c = 0; c < FF / 4; ++c) {
        const float4 v = *(const float4*)(xp + c * 4);
        xv[c*4+0] = v.x; xv[c*4+1] = v.y; xv[c*4+2] = v.z; xv[c*4+3] = v.w;
    }

    float acc[24];
#pragma unroll
    for (int g = 0; g < 24; ++g) acc[g] = 0.0f;
    float sum = 0.0f;

#pragma unroll
    for (int t = 0; t < 4; ++t) {            // score tile [t*8, t*8+8)
        // s_tile = ba + x @ Wa[:, tile]   (Wa addresses wave-uniform -> SGPR)
        float s[8];
#pragma unroll
        for (int k = 0; k < 8; ++k) s[k] = ba[t * 8 + k];
#pragma unroll
        for (int f = 0; f < FF; ++f) {
            const float xf = xv[f];
            const float* wr = Wa + f * FF + t * 8;
#pragma unroll
            for (int k = 0; k < 8; ++k) s[k] = fmaf(xf, wr[k], s[k]);
        }
        // exp (no max-sub: |s| small, fp32 safe) + project into acc
#pragma unroll
        for (int k = 0; k < 8; ++k) {
            const float e = __expf(s[k]);
            sum += e;
            const float p = xv[t * 8 + k] * e;       // feat*e (1/sum at end)
            const float* wl = Wl + (size_t)(t * 8 + k) * 24;  // wave-uniform -> SGPR
#pragma unroll
            for (int g = 0; g < 24; ++g) acc[g] = fmaf(p, wl[g], acc[g]);
        }
    }
    const float r = fast_rcp(sum);

    // epilogue: gate-major acc -> [unit][i,f,g,o], scale by r, add bl
    float* op = xz + (size_t)tid * 24;
#pragma unroll
    for (int jp = 0; jp < HH; ++jp) {
        float4 v;
        v.x = fmaf(acc[0  + jp], r, bl[0  + jp]);   // i
        v.y = fmaf(acc[6  + jp], r, bl[6  + jp]);   // f
        v.z = fmaf(acc[12 + jp], r, bl[12 + jp]);   // g pre-act
        v.w = fmaf(acc[18 + jp], r, bl[18 + jp]);   // o
        *(float4*)(op + jp * 4) = v;
    }
}

// K2 (unchanged, passing): LSTM scan. 8 lanes/batch, DPP cross-lane,
// W10 in LDS, 12-step-deep prefetch.
__global__ __launch_bounds__(64, 1) void k_scan(
    const float* __restrict__ xz, const float* __restrict__ Ul,
    const float* __restrict__ W10, const float* __restrict__ b10,
    const float* __restrict__ Wo, const float* __restrict__ bo,
    float* __restrict__ out)
{
    const int lane = threadIdx.x;
    const int j = lane & 7;
    const int b = blockIdx.x * 8 + (lane >> 3);
    const bool real = (j < HH);
    const int jc = real ? j : 0;

    __shared__ __align__(16) float w10s[TT * HH * 10 + 64];  // +junk row for t=256 prefetch
    {
        const float2* src = (const float2*)W10;
        float2* dst = (float2*)w10s;
        for (int i = lane; i < (TT * HH * 10) / 2; i += 64) dst[i] = src[i];
    }
    __syncthreads();

    float Ui[8], Uf[8], Ug[8], Uo[8];
#pragma unroll
    for (int m = 0; m < 8; ++m) {
        const int src = j ^ m;
        const bool ok = real && (src < HH);
        const float* row = Ul + (ok ? src : 0) * 24;
        Ui[m] = ok ? row[0  + j] : 0.0f;
        Uf[m] = ok ? row[6  + j] : 0.0f;
        Ug[m] = ok ? row[12 + j] : 0.0f;
        Uo[m] = ok ? row[18 + j] : 0.0f;
    }

    float hl[8];           // ovec = ov*ec of unit (j^m); true h = ovec * r2
    float r2 = 1.0f;
    float c = 0.0f;
    float y[10];
#pragma unroll
    for (int m = 0; m < 8; ++m) hl[m] = 0.0f;
#pragma unroll
    for (int p = 0; p < 10; ++p) y[p] = 0.0f;

    float2 wrow[5];
#pragma unroll
    for (int q = 0; q < 5; ++q) wrow[q] = *(const float2*)(w10s + jc * 10 + q * 2);

    const float* xb = xz + (size_t)b * (TT * 24) + j * 4;

    auto step = [&](const float4 z4, const int t) {
        float di0 = hl[0]*Ui[0], di1 = hl[4]*Ui[4];
        float df0 = hl[0]*Uf[0], df1 = hl[4]*Uf[4];
        float dg0 = hl[0]*Ug[0], dg1 = hl[4]*Ug[4];
        float dq0 = hl[0]*Uo[0], dq1 = hl[4]*Uo[4];
#pragma unroll
        for (int m = 1; m < 4; ++m) {
            di0 = fmaf(hl[m], Ui[m], di0); di1 = fmaf(hl[m+4], Ui[m+4], di1);
            df0 = fmaf(hl[m], Uf[m], df0); df1 = fmaf(hl[m+4], Uf[m+4], df1);
            dg0 = fmaf(hl[m], Ug[m], dg0); dg1 = fmaf(hl[m+4], Ug[m+4], dg1);
            dq0 = fmaf(hl[m], Uo[m], dq0); dq1 = fmaf(hl[m+4], Uo[m+4], dq1);
        }
        const float zi = fmaf(di0 + di1, r2, z4.x);
        const float zf = fmaf(df0 + df1, r2, z4.y);
        const float zg = fmaf(dg0 + dg1, r2, z4.z);
        const float zo = fmaf(dq0 + dq1, r2, z4.w);

        const float iv = sigmoidf(zi);
        const float fv = sigmoidf(zf);
        const float ov = sigmoidf(zo);

        const float eg = real ? __expf(zg) : 0.0f;
        float s1 = eg;
        s1 += dppf<DPP_XOR1>(s1);
        s1 += dppf<DPP_XOR2>(s1);
        s1 += dpp_xor4(s1);
        c = fmaf(fv, c, (iv * eg) * fast_rcp(s1));

        const float cmsk = real ? c : -1e30f;
        float m2 = fmaxf(cmsk, dppf<DPP_XOR1>(cmsk));
        m2 = fmaxf(m2, dppf<DPP_XOR2>(m2));
        m2 = fmaxf(m2, dpp_xor4(m2));
        const float ec = real ? __expf(c - m2) : 0.0f;
        float s2 = ec;
        s2 += dppf<DPP_XOR1>(s2);
        s2 += dppf<DPP_XOR2>(s2);
        s2 += dpp_xor4(s2);

        const float ovec = ov * ec;
        hl[0] = ovec;
        hl[1] = dppf<DPP_XOR1>(ovec);
        hl[2] = dppf<DPP_XOR2>(ovec);
        hl[3] = dppf<DPP_XOR3>(ovec);
        const float h7 = dppf<DPP_HALF>(ovec);
        hl[7] = h7;
        hl[6] = dppf<DPP_XOR1>(h7);
        hl[5] = dppf<DPP_XOR2>(h7);
        hl[4] = dppf<DPP_XOR3>(h7);
        r2 = fast_rcp(s2);
        const float hn = ovec * r2;

        float2 wn[5];
        const int rn = ((t + 1) * HH + jc) * 10;
#pragma unroll
        for (int q = 0; q < 5; ++q) wn[q] = *(const float2*)(w10s + rn + q * 2);
#pragma unroll
        for (int q = 0; q < 5; ++q) {
            y[2*q]   = fmaf(hn, wrow[q].x, y[2*q]);
            y[2*q+1] = fmaf(hn, wrow[q].y, y[2*q+1]);
        }
#pragma unroll
        for (int q = 0; q < 5; ++q) wrow[q] = wn[q];
    };

    float4 A[4], B[4], C[4], D[4];
    const float* xp = xb;

#define LDBLK(Bf, dt0)                                                  \
    { _Pragma("unroll") for (int q = 0; q < 4; ++q)                     \
        Bf[q] = *(const float4*)(xp + (dt0 + q) * 24); }

    LDBLK(A, 0); LDBLK(B, 4); LDBLK(C, 8);

#pragma unroll 1
    for (int it = 0; it < 16; ++it) {
        const int t0 = it * 16;
        LDBLK(D, 12);
        step(A[0], t0 + 0);  step(A[1], t0 + 1);  step(A[2], t0 + 2);  step(A[3], t0 + 3);
        LDBLK(A, 16);
        step(B[0], t0 + 4);  step(B[1], t0 + 5);  step(B[2], t0 + 6);  step(B[3], t0 + 7);
        LDBLK(B, 20);
        step(C[0], t0 + 8);  step(C[1], t0 + 9);  step(C[2], t0 + 10); step(C[3], t0 + 11);
        LDBLK(C, 24);
        step(D[0], t0 + 12); step(D[1], t0 + 13); step(D[2], t0 + 14); step(D[3], t0 + 15);
        xp += 16 * 24;
    }
#undef LDBLK

#pragma unroll
    for (int p = 0; p < 10; ++p) {
        float v = y[p];
        v += dppf<DPP_XOR1>(v);
        v += dppf<DPP_XOR2>(v);
        v += dpp_xor4(v);
        y[p] = v;
    }

    float o8 = bo[j];
#pragma unroll
    for (int p = 0; p < 10; ++p) o8 = fmaf(y[p] + b10[p], Wo[p * 8 + j], o8);
    out[(size_t)b * 8 + j] = o8;
}

extern "C" void kernel_launch(void* const* d_in, const int* in_sizes, int n_in,
                              void* d_out, int out_size, void* d_ws, size_t ws_size,
                              hipStream_t stream) {
    const float* x   = (const float*)d_in[0];
    const float* Wa  = (const float*)d_in[1];
    const float* ba  = (const float*)d_in[2];
    const float* Wl  = (const float*)d_in[3];
    const float* Ul  = (const float*)d_in[4];
    const float* bl  = (const float*)d_in[5];
    const float* W10 = (const float*)d_in[6];
    const float* b10 = (const float*)d_in[7];
    const float* Wo  = (const float*)d_in[8];
    const float* bo  = (const float*)d_in[9];
    float* out = (float*)d_out;
    float* xz  = (float*)d_ws;   // BB*TT*24*4 = 96 MiB (+ slack for tail prefetch)

    hipLaunchKernelGGL(k_attn_xz, dim3(BB * TT / 256), dim3(256), 0, stream,
                       x, Wa, ba, Wl, bl, xz);
    hipLaunchKernelGGL(k_scan, dim3(BB / 8), dim3(64), 0, stream,
                       xz, Ul, W10, b10, Wo, bo, out);
}